// Round 1
// 761.360 us; speedup vs baseline: 1.0811x; 1.0811x over previous
//
#include <hip/hip_runtime.h>

#define N_TOK 2048
#define H_DIM 2048
#define I_DIM 1408
#define E_EXP 64
#define G_GRP 8
#define KTOT  (G_GRP * I_DIM)   // 11264
#define NQ    (G_GRP * I_DIM * H_DIM / 4)   // quads per weight array = 5,767,168
#define NQB   (NQ / 256)                    // 22528 blocks per array

typedef __bf16 bf16x8 __attribute__((ext_vector_type(8)));
typedef float f32x4 __attribute__((ext_vector_type(4)));

__device__ __forceinline__ unsigned short f2bf(float f) {
    unsigned int u = __builtin_bit_cast(unsigned int, f);
    u += 0x7fffu + ((u >> 16) & 1u);   // RNE
    return (unsigned short)(u >> 16);
}

__device__ __forceinline__ void gl_lds16(const void* g, void* l) {
    __builtin_amdgcn_global_load_lds(
        (const __attribute__((address_space(1))) unsigned int*)g,
        (__attribute__((address_space(3))) unsigned int*)l, 16, 0, 0);
}

// XOR-swizzled LDS chunk addressing for BK=64 tiles (k_gemm2): slot(row,c)=row*8+(c^(row&7)); 16B chunks.
__device__ __forceinline__ bf16x8 lds_frag(const unsigned short* sm, int row, int c) {
    return *(const bf16x8*)&sm[(row * 8 + (c ^ (row & 7))) * 8];
}

// XOR-swizzled addressing for BK=32 tiles (k_gemm1): slot(row,q)=region+row*4+(q^(row&3)); 16B chunks.
__device__ __forceinline__ bf16x8 frag32(const unsigned short* sm, int region, int row, int q) {
    return *(const bf16x8*)&sm[(region + row * 4 + (q ^ (row & 3))) * 8];
}

// ---------- prep: 3x fp32->bf16 weight cvt (+wd transpose) + gate_w transpose ----------
__global__ __launch_bounds__(256) void k_prep(const float* __restrict__ gw,
                                              const float* __restrict__ wgp,
                                              const float* __restrict__ wup,
                                              const float* __restrict__ wdp,
                                              float* __restrict__ gwT,
                                              unsigned short* __restrict__ wgB,
                                              unsigned short* __restrict__ wuB,
                                              unsigned short* __restrict__ wdB) {
    int b = blockIdx.x, t = threadIdx.x;
    if (b < 2 * NQB) {   // layout-preserving cvt of wg / wu
        const float* in = (b < NQB) ? wgp : wup;
        unsigned short* out = (b < NQB) ? wgB : wuB;
        int i = (b < NQB ? b : b - NQB) * 256 + t;
        float4 v = ((const float4*)in)[i];
        ushort4 o;
        o.x = f2bf(v.x); o.y = f2bf(v.y); o.z = f2bf(v.z); o.w = f2bf(v.w);
        ((ushort4*)out)[i] = o;
    } else if (b < 3 * NQB) {  // wd: [g][h][i] f32 -> [h][g*I+i] bf16
        int idx = (b - 2 * NQB) * 256 + t;
        int i4 = idx % (I_DIM / 4);
        int h  = (idx / (I_DIM / 4)) & (H_DIM - 1);
        int g  = idx / ((I_DIM / 4) * H_DIM);
        float4 v = ((const float4*)(wdp + ((size_t)g * H_DIM + h) * I_DIM))[i4];
        ushort4 o;
        o.x = f2bf(v.x); o.y = f2bf(v.y); o.z = f2bf(v.z); o.w = f2bf(v.w);
        ((ushort4*)(wdB + ((size_t)h * G_GRP + g) * I_DIM))[i4] = o;
    } else {                   // gate_w transpose [64][2048] -> [2048][64]
        int i = (b - 3 * NQB) * 256 + t;
        gwT[i] = gw[(i & 63) * H_DIM + (i >> 6)];
    }
}

// ---------------- gating: logits (f64 acc) + softmax + top8 + group softmax ----------------
__global__ __launch_bounds__(512) void k_gating(const float* __restrict__ x,
                                                const float* __restrict__ gwT,
                                                float* __restrict__ soft,
                                                float* __restrict__ scal) {
    __shared__ double smAcc[8][8][64];
    int t = threadIdx.x, wid = t >> 6, lane = t & 63;
    int n0 = blockIdx.x * 8;

    double acc[8];
#pragma unroll
    for (int k = 0; k < 8; ++k) acc[k] = 0.0;
    int h0 = wid * 256;
    for (int h = h0; h < h0 + 256; ++h) {
        float gv = gwT[h * 64 + lane];
#pragma unroll
        for (int tok = 0; tok < 8; ++tok)
            acc[tok] += (double)x[(size_t)(n0 + tok) * H_DIM + h] * (double)gv;
    }
#pragma unroll
    for (int tok = 0; tok < 8; ++tok) smAcc[wid][tok][lane] = acc[tok];
    __syncthreads();

    double lg = 0.0;
#pragma unroll
    for (int w2 = 0; w2 < 8; ++w2) lg += smAcc[w2][wid][lane];
    float logit = (float)lg;

    float mx = logit;
#pragma unroll
    for (int d = 1; d < 64; d <<= 1) mx = fmaxf(mx, __shfl_xor(mx, d));
    float ex = expf(logit - mx);
    float sm = ex;
#pragma unroll
    for (int d = 1; d < 64; d <<= 1) sm += __shfl_xor(sm, d);
    float prob = ex / sm;

    float cur = prob, w = 0.0f;
#pragma unroll
    for (int it = 0; it < 8; ++it) {
        float m = cur;
#pragma unroll
        for (int d = 1; d < 64; d <<= 1) m = fmaxf(m, __shfl_xor(m, d));
        unsigned long long msk = __ballot(cur == m);
        int first = __ffsll(msk) - 1;
        if (lane == first) { w = prob; cur = -1.0f; }
    }
    float wf = w;

    float s8 = wf;
#pragma unroll
    for (int d = 1; d < 8; d <<= 1) s8 += __shfl_xor(s8, d);
    float v = (wf == 0.0f) ? -1000000000.0f : wf;
    float m8 = v;
#pragma unroll
    for (int d = 1; d < 8; d <<= 1) m8 = fmaxf(m8, __shfl_xor(m8, d));
    float e8 = expf(v - m8);
    float q8 = e8;
#pragma unroll
    for (int d = 1; d < 8; d <<= 1) q8 += __shfl_xor(q8, d);

    int n = n0 + wid;
    soft[(size_t)n * 64 + lane] = e8 / q8;
    if ((lane & 7) == 0) scal[(size_t)n * 8 + (lane >> 3)] = s8;
}

// ------- xg[g][n][h] = bf16(x + soft.mu), vectorized: thread owns 4 h-cols, mu in regs -------
__global__ __launch_bounds__(256) void k_xg(const float* __restrict__ x,
                                            const float* __restrict__ muw,
                                            const float* __restrict__ soft,
                                            unsigned short* __restrict__ xg) {
    int g = blockIdx.z, h0 = blockIdx.y * 1024, n0 = blockIdx.x * 128;
    __shared__ float smSf[128][8];
    int t = threadIdx.x;
    {
        int r = t >> 1, s4 = (t & 1) * 4;
        float4 sv = *(const float4*)&soft[(size_t)(n0 + r) * 64 + g * 8 + s4];
        smSf[r][s4 + 0] = sv.x; smSf[r][s4 + 1] = sv.y;
        smSf[r][s4 + 2] = sv.z; smSf[r][s4 + 3] = sv.w;
    }
    int hh = t * 4;
    float mu[8][4];
#pragma unroll
    for (int j = 0; j < 4; ++j) {
        const float4* p = (const float4*)(muw + ((size_t)g * H_DIM + h0 + hh + j) * 8);
        float4 a = p[0], b = p[1];
        mu[0][j] = a.x; mu[1][j] = a.y; mu[2][j] = a.z; mu[3][j] = a.w;
        mu[4][j] = b.x; mu[5][j] = b.y; mu[6][j] = b.z; mu[7][j] = b.w;
    }
    __syncthreads();
    for (int r = 0; r < 128; ++r) {
        float4 xv = *(const float4*)&x[(size_t)(n0 + r) * H_DIM + h0 + hh];
        float c0 = xv.x, c1 = xv.y, c2 = xv.z, c3 = xv.w;
#pragma unroll
        for (int s = 0; s < 8; ++s) {
            float w = smSf[r][s];
            c0 += w * mu[s][0]; c1 += w * mu[s][1];
            c2 += w * mu[s][2]; c3 += w * mu[s][3];
        }
        ushort4 o;
        o.x = f2bf(c0); o.y = f2bf(c1); o.z = f2bf(c2); o.w = f2bf(c3);
        *(ushort4*)&xg[((size_t)g * N_TOK + n0 + r) * H_DIM + h0 + hh] = o;
    }
}

// ---- gemm1: 256m x 128n dual-output (gate+up) tile, 8 waves (2M x 4N), BK=32 ----
// T3+T4+T5: 4-deep LDS ring (4 x 32KB = 128KB), stage tile t+3 while computing
// tile t, ONE counted s_waitcnt vmcnt(8) per K-tile (never 0 in steady state),
// raw s_barrier (no __syncthreads vmcnt-drain), setprio(1) around MFMA clusters.
// 2 phases per K-tile (m-half split), 16 MFMA + 8/4 ds_read_b128 per phase.
// a'[n][g*I+i] = scal[n,g] * silu(xg_g @ Wg^T) * (xg_g @ Wu^T)   (bf16)
#define NT_G1 (H_DIM / 32)   // 64 K-tiles

__global__ __launch_bounds__(512, 2) void k_gemm1(const unsigned short* __restrict__ xg,
                                                  const unsigned short* __restrict__ wg,
                                                  const unsigned short* __restrict__ wu,
                                                  const float* __restrict__ scal,
                                                  unsigned short* __restrict__ aB) {
    int f = blockIdx.x;
    int g = f & 7, r = f >> 3;          // r in [0,88)
    int m0 = (r & 7) * 256;             // 8 m-tiles
    int n0 = (r >> 3) * 128;            // 11 n-tiles
    // 4 ring buffers x 2048 chunks (A: slots 0..1023 = 256r x 4c | G: 1024..1535 | U: 1536..2047)
    __shared__ __align__(16) unsigned short lds[4 * 2048 * 8];   // 128 KB
    __shared__ float smS[256];
    int t = threadIdx.x, wid = t >> 6, lane = t & 63;
    int r16 = lane & 15, quad = lane >> 4;
    int wm = wid >> 2, wn = wid & 3;

    if (t < 256) smS[t] = scal[(size_t)(m0 + t) * 8 + g];

    const unsigned short* A  = xg + (size_t)g * N_TOK * H_DIM;
    const unsigned short* Bg = wg + (size_t)g * I_DIM * H_DIM;
    const unsigned short* Bu = wu + (size_t)g * I_DIM * H_DIM;

    // per-thread staging sources: slot s holds global chunk (row=s>>2, c=(s&3)^(row&3))
    int sA0 = (wid * 2 + 0) * 64 + lane;
    int sA1 = (wid * 2 + 1) * 64 + lane;
    int rA0 = sA0 >> 2, cA0 = (sA0 & 3) ^ (rA0 & 3);
    int rA1 = sA1 >> 2, cA1 = (sA1 & 3) ^ (rA1 & 3);
    int sB = wid * 64 + lane;
    int rB = sB >> 2, cB = (sB & 3) ^ (rB & 3);
    const unsigned short* gA0 = A + (size_t)(m0 + rA0) * H_DIM + cA0 * 8;
    const unsigned short* gA1 = A + (size_t)(m0 + rA1) * H_DIM + cA1 * 8;
    const unsigned short* gG  = Bg + (size_t)(n0 + rB) * H_DIM + cB * 8;
    const unsigned short* gU  = Bu + (size_t)(n0 + rB) * H_DIM + cB * 8;

#define STAGE_A(ts) do { int b_ = (ts) & 3; \
        gl_lds16(gA0 + (size_t)(ts) * 32, &lds[((size_t)b_ * 2048 + (wid * 2 + 0) * 64) * 8]); \
        gl_lds16(gA1 + (size_t)(ts) * 32, &lds[((size_t)b_ * 2048 + (wid * 2 + 1) * 64) * 8]); } while (0)
#define STAGE_GU(ts) do { int b_ = (ts) & 3; \
        gl_lds16(gG + (size_t)(ts) * 32, &lds[((size_t)b_ * 2048 + 1024 + wid * 64) * 8]); \
        gl_lds16(gU + (size_t)(ts) * 32, &lds[((size_t)b_ * 2048 + 1536 + wid * 64) * 8]); } while (0)

    f32x4 zero = {0.f, 0.f, 0.f, 0.f};
    f32x4 accg[8][2], accu[8][2];
#pragma unroll
    for (int mi = 0; mi < 8; ++mi)
#pragma unroll
        for (int ni = 0; ni < 2; ++ni) { accg[mi][ni] = zero; accu[mi][ni] = zero; }

    // prologue: 3 K-tiles in flight; tile 0 (+scal load) drained, 8 newest stay pending
    STAGE_A(0); STAGE_GU(0);
    STAGE_A(1); STAGE_GU(1);
    STAGE_A(2); STAGE_GU(2);
    asm volatile("s_waitcnt vmcnt(8) lgkmcnt(0)" ::: "memory");
    __builtin_amdgcn_s_barrier();

    for (int tt = 0; tt < NT_G1; ++tt) {
        const unsigned short* buf = &lds[(size_t)(tt & 3) * 2048 * 8];
        bf16x8 af[4], bgf[2], buf_[2];
        // ---- phase 0: m-half 0 (mi 0..3) ----
#pragma unroll
        for (int mi = 0; mi < 4; ++mi)
            af[mi] = frag32(buf, 0, wm * 128 + mi * 16 + r16, quad);
#pragma unroll
        for (int ni = 0; ni < 2; ++ni) {
            bgf[ni]  = frag32(buf, 1024, wn * 32 + ni * 16 + r16, quad);
            buf_[ni] = frag32(buf, 1536, wn * 32 + ni * 16 + r16, quad);
        }
        if (tt + 3 < NT_G1) STAGE_A(tt + 3);   // into buf (tt+3)&3 == (tt-1)&3: read-complete
        __builtin_amdgcn_s_barrier();
        __builtin_amdgcn_s_setprio(1);
#pragma unroll
        for (int mi = 0; mi < 4; ++mi)
#pragma unroll
            for (int ni = 0; ni < 2; ++ni) {
                accg[mi][ni] = __builtin_amdgcn_mfma_f32_16x16x32_bf16(af[mi], bgf[ni], accg[mi][ni], 0, 0, 0);
                accu[mi][ni] = __builtin_amdgcn_mfma_f32_16x16x32_bf16(af[mi], buf_[ni], accu[mi][ni], 0, 0, 0);
            }
        __builtin_amdgcn_s_setprio(0);
        __builtin_amdgcn_s_barrier();
        // ---- phase 1: m-half 1 (mi 4..7), B frags reused ----
#pragma unroll
        for (int mi = 0; mi < 4; ++mi)
            af[mi] = frag32(buf, 0, wm * 128 + (mi + 4) * 16 + r16, quad);
        if (tt + 3 < NT_G1) STAGE_GU(tt + 3);
        __builtin_amdgcn_s_barrier();
        __builtin_amdgcn_s_setprio(1);
#pragma unroll
        for (int mi = 0; mi < 4; ++mi)
#pragma unroll
            for (int ni = 0; ni < 2; ++ni) {
                accg[mi + 4][ni] = __builtin_amdgcn_mfma_f32_16x16x32_bf16(af[mi], bgf[ni], accg[mi + 4][ni], 0, 0, 0);
                accu[mi + 4][ni] = __builtin_amdgcn_mfma_f32_16x16x32_bf16(af[mi], buf_[ni], accu[mi + 4][ni], 0, 0, 0);
            }
        __builtin_amdgcn_s_setprio(0);
        // counted wait: tile tt+1 must be landed; tiles tt+2, tt+3 stay in flight
        {
            int rem = NT_G1 - 2 - tt;
            if (rem >= 2)      asm volatile("s_waitcnt vmcnt(8)" ::: "memory");
            else if (rem == 1) asm volatile("s_waitcnt vmcnt(4)" ::: "memory");
            else if (rem == 0) asm volatile("s_waitcnt vmcnt(0)" ::: "memory");
        }
        __builtin_amdgcn_s_barrier();
    }
#undef STAGE_A
#undef STAGE_GU

#pragma unroll
    for (int mi = 0; mi < 8; ++mi)
#pragma unroll
        for (int ni = 0; ni < 2; ++ni)
#pragma unroll
            for (int rr = 0; rr < 4; ++rr) {
                int rl = wm * 128 + mi * 16 + quad * 4 + rr;
                int row = m0 + rl;
                int col = n0 + wn * 32 + ni * 16 + r16;
                float gv = accg[mi][ni][rr];
                float sv = gv / (1.0f + __expf(-gv));
                aB[((size_t)row * G_GRP + g) * I_DIM + col] = f2bf(sv * accu[mi][ni][rr] * smS[rl]);
            }
}

// ---------------- gemm2: y[n,h] = A'[n,:] . Wd'[h,:], K=11264, split-K=2 + atomicAdd ----------------
__global__ __launch_bounds__(256) void k_gemm2(const unsigned short* __restrict__ aB,
                                               const unsigned short* __restrict__ wd,
                                               float* __restrict__ out) {
    int m0 = blockIdx.x * 128, h0 = blockIdx.y * 128;
    int kbase = blockIdx.z * (KTOT / 2);
    __shared__ __align__(16) unsigned short smA[8192], smB[8192];
    int t = threadIdx.x, wid = t >> 6, lane = t & 63;
    int r16 = lane & 15, quad = lane >> 4;
    int wm = wid >> 1, wn = wid & 1;

    f32x4 zero = {0.f, 0.f, 0.f, 0.f};
    f32x4 acc[4][4];
#pragma unroll
    for (int mi = 0; mi < 4; ++mi)
#pragma unroll
        for (int ni = 0; ni < 4; ++ni) acc[mi][ni] = zero;

    for (int k0 = kbase; k0 < kbase + KTOT / 2; k0 += 64) {
#pragma unroll
        for (int j = 0; j < 4; ++j) {
            int issue = wid * 4 + j;
            int s = issue * 64 + lane;
            int row = s >> 3;
            int c = (s & 7) ^ (row & 7);
            gl_lds16(aB + (size_t)(m0 + row) * KTOT + k0 + c * 8, &smA[issue * 512]);
            gl_lds16(wd + (size_t)(h0 + row) * KTOT + k0 + c * 8, &smB[issue * 512]);
        }
        __syncthreads();
#pragma unroll
        for (int kh = 0; kh < 2; ++kh) {
            int cc = kh * 4 + quad;
            bf16x8 af[4], bf_[4];
#pragma unroll
            for (int mi = 0; mi < 4; ++mi) af[mi]  = lds_frag(smA, wm * 64 + mi * 16 + r16, cc);
#pragma unroll
            for (int ni = 0; ni < 4; ++ni) bf_[ni] = lds_frag(smB, wn * 64 + ni * 16 + r16, cc);
#pragma unroll
            for (int mi = 0; mi < 4; ++mi)
#pragma unroll
                for (int ni = 0; ni < 4; ++ni)
                    acc[mi][ni] = __builtin_amdgcn_mfma_f32_16x16x32_bf16(af[mi], bf_[ni], acc[mi][ni], 0, 0, 0);
        }
        __syncthreads();
    }

#pragma unroll
    for (int mi = 0; mi < 4; ++mi)
#pragma unroll
        for (int ni = 0; ni < 4; ++ni)
#pragma unroll
            for (int rr = 0; rr < 4; ++rr) {
                int row = m0 + wm * 64 + mi * 16 + quad * 4 + rr;
                int col = h0 + wn * 64 + ni * 16 + r16;
                atomicAdd(&out[(size_t)row * H_DIM + col], acc[mi][ni][rr]);
            }
}

extern "C" void kernel_launch(void* const* d_in, const int* in_sizes, int n_in,
                              void* d_out, int out_size, void* d_ws, size_t ws_size,
                              hipStream_t stream) {
    const float* x   = (const float*)d_in[0];
    const float* gw  = (const float*)d_in[1];
    const float* mu  = (const float*)d_in[2];
    const float* wgp = (const float*)d_in[3];
    const float* wup = (const float*)d_in[4];
    const float* wdp = (const float*)d_in[5];
    float* out = (float*)d_out;
    char* ws = (char*)d_ws;

    // workspace layout (241.1 MB total)
    float* gwT  = (float*)(ws + 0);                      // 512 KB
    float* soft = (float*)(ws + 524288);                 // 512 KB
    float* scal = (float*)(ws + 1048576);                // 64 KB
    unsigned short* wgB = (unsigned short*)(ws + 1114112);    // 44 MB [g][i][h]
    unsigned short* wuB = (unsigned short*)(ws + 47251456);   // 44 MB [g][i][h]
    unsigned short* wdB = (unsigned short*)(ws + 93388800);   // 44 MB [h][g*I+i]
    unsigned short* xg  = (unsigned short*)(ws + 139526144);  // 64 MB [g][n][h]
    unsigned short* aB  = (unsigned short*)(ws + 206635008);  // 44 MB [n][g*I+i]

    hipMemsetAsync(d_out, 0, (size_t)N_TOK * H_DIM * sizeof(float), stream);
    k_prep<<<3 * NQB + 512, 256, 0, stream>>>(gw, wgp, wup, wdp, gwT, wgB, wuB, wdB);
    k_gating<<<N_TOK / 8, 512, 0, stream>>>(x, gwT, soft, scal);
    k_xg<<<dim3(16, 2, 8), 256, 0, stream>>>(x, mu, soft, xg);
    k_gemm1<<<704, 512, 0, stream>>>(xg, wgB, wuB, scal, aB);
    k_gemm2<<<dim3(16, 16, 2), 256, 0, stream>>>(aB, wdB, out);
}

// Round 2
// 736.854 us; speedup vs baseline: 1.1170x; 1.0333x over previous
//
#include <hip/hip_runtime.h>

#define N_TOK 2048
#define H_DIM 2048
#define I_DIM 1408
#define E_EXP 64
#define G_GRP 8
#define KTOT  (G_GRP * I_DIM)   // 11264
#define NQ    (G_GRP * I_DIM * H_DIM / 4)   // quads per weight array = 5,767,168
#define NQB   (NQ / 256)                    // 22528 blocks per array

typedef __bf16 bf16x8 __attribute__((ext_vector_type(8)));
typedef float f32x4 __attribute__((ext_vector_type(4)));

__device__ __forceinline__ unsigned short f2bf(float f) {
    unsigned int u = __builtin_bit_cast(unsigned int, f);
    u += 0x7fffu + ((u >> 16) & 1u);   // RNE
    return (unsigned short)(u >> 16);
}

__device__ __forceinline__ void gl_lds16(const void* g, void* l) {
    __builtin_amdgcn_global_load_lds(
        (const __attribute__((address_space(1))) unsigned int*)g,
        (__attribute__((address_space(3))) unsigned int*)l, 16, 0, 0);
}

// Paired-row XOR swizzle for BK=32 tiles: two 64B rows share one 128B line so the
// XOR spans the full 8x16B bank period.  slot(row,q) = (row>>1)*8 + ((q+4*(row&1)) ^ ((row>>1)&7)).
// Any 16-aligned 16-row fragment read at fixed q hits each 16B bank-group exactly 2x per quad (free).
__device__ __forceinline__ bf16x8 fragP(const unsigned short* sm, int region, int row, int q) {
    int idx = region + ((row >> 1) << 3) + ((q | ((row & 1) << 2)) ^ ((row >> 1) & 7));
    return *(const bf16x8*)&sm[idx * 8];
}
// inverse map: linear LDS slot s -> (row, chunk q) of the global tile
__device__ __forceinline__ int slot_row(int s) {
    int line = s >> 3, u = (s & 7) ^ (line & 7);
    return (line << 1) | (u >> 2);
}
__device__ __forceinline__ int slot_q(int s) {
    int line = s >> 3, u = (s & 7) ^ (line & 7);
    return u & 3;
}

// ---------- prep: 3x fp32->bf16 weight cvt (+wd transpose) + gate_w transpose ----------
__global__ __launch_bounds__(256) void k_prep(const float* __restrict__ gw,
                                              const float* __restrict__ wgp,
                                              const float* __restrict__ wup,
                                              const float* __restrict__ wdp,
                                              float* __restrict__ gwT,
                                              unsigned short* __restrict__ wgB,
                                              unsigned short* __restrict__ wuB,
                                              unsigned short* __restrict__ wdB) {
    int b = blockIdx.x, t = threadIdx.x;
    if (b < 2 * NQB) {   // layout-preserving cvt of wg / wu
        const float* in = (b < NQB) ? wgp : wup;
        unsigned short* out = (b < NQB) ? wgB : wuB;
        int i = (b < NQB ? b : b - NQB) * 256 + t;
        float4 v = ((const float4*)in)[i];
        ushort4 o;
        o.x = f2bf(v.x); o.y = f2bf(v.y); o.z = f2bf(v.z); o.w = f2bf(v.w);
        ((ushort4*)out)[i] = o;
    } else if (b < 3 * NQB) {  // wd: [g][h][i] f32 -> [h][g*I+i] bf16
        int idx = (b - 2 * NQB) * 256 + t;
        int i4 = idx % (I_DIM / 4);
        int h  = (idx / (I_DIM / 4)) & (H_DIM - 1);
        int g  = idx / ((I_DIM / 4) * H_DIM);
        float4 v = ((const float4*)(wdp + ((size_t)g * H_DIM + h) * I_DIM))[i4];
        ushort4 o;
        o.x = f2bf(v.x); o.y = f2bf(v.y); o.z = f2bf(v.z); o.w = f2bf(v.w);
        ((ushort4*)(wdB + ((size_t)h * G_GRP + g) * I_DIM))[i4] = o;
    } else {                   // gate_w transpose [64][2048] -> [2048][64]
        int i = (b - 3 * NQB) * 256 + t;
        gwT[i] = gw[(i & 63) * H_DIM + (i >> 6)];
    }
}

// ---------------- gating: logits (f64 acc) + softmax + top8 + group softmax ----------------
__global__ __launch_bounds__(512) void k_gating(const float* __restrict__ x,
                                                const float* __restrict__ gwT,
                                                float* __restrict__ soft,
                                                float* __restrict__ scal) {
    __shared__ double smAcc[8][8][64];
    int t = threadIdx.x, wid = t >> 6, lane = t & 63;
    int n0 = blockIdx.x * 8;

    double acc[8];
#pragma unroll
    for (int k = 0; k < 8; ++k) acc[k] = 0.0;
    int h0 = wid * 256;
    for (int h = h0; h < h0 + 256; ++h) {
        float gv = gwT[h * 64 + lane];
#pragma unroll
        for (int tok = 0; tok < 8; ++tok)
            acc[tok] += (double)x[(size_t)(n0 + tok) * H_DIM + h] * (double)gv;
    }
#pragma unroll
    for (int tok = 0; tok < 8; ++tok) smAcc[wid][tok][lane] = acc[tok];
    __syncthreads();

    double lg = 0.0;
#pragma unroll
    for (int w2 = 0; w2 < 8; ++w2) lg += smAcc[w2][wid][lane];
    float logit = (float)lg;

    float mx = logit;
#pragma unroll
    for (int d = 1; d < 64; d <<= 1) mx = fmaxf(mx, __shfl_xor(mx, d));
    float ex = expf(logit - mx);
    float sm = ex;
#pragma unroll
    for (int d = 1; d < 64; d <<= 1) sm += __shfl_xor(sm, d);
    float prob = ex / sm;

    float cur = prob, w = 0.0f;
#pragma unroll
    for (int it = 0; it < 8; ++it) {
        float m = cur;
#pragma unroll
        for (int d = 1; d < 64; d <<= 1) m = fmaxf(m, __shfl_xor(m, d));
        unsigned long long msk = __ballot(cur == m);
        int first = __ffsll(msk) - 1;
        if (lane == first) { w = prob; cur = -1.0f; }
    }
    float wf = w;

    float s8 = wf;
#pragma unroll
    for (int d = 1; d < 8; d <<= 1) s8 += __shfl_xor(s8, d);
    float v = (wf == 0.0f) ? -1000000000.0f : wf;
    float m8 = v;
#pragma unroll
    for (int d = 1; d < 8; d <<= 1) m8 = fmaxf(m8, __shfl_xor(m8, d));
    float e8 = expf(v - m8);
    float q8 = e8;
#pragma unroll
    for (int d = 1; d < 8; d <<= 1) q8 += __shfl_xor(q8, d);

    int n = n0 + wid;
    soft[(size_t)n * 64 + lane] = e8 / q8;
    if ((lane & 7) == 0) scal[(size_t)n * 8 + (lane >> 3)] = s8;
}

// ------- xg[g][n][h] = bf16(x + soft.mu), vectorized: thread owns 4 h-cols, mu in regs -------
__global__ __launch_bounds__(256) void k_xg(const float* __restrict__ x,
                                            const float* __restrict__ muw,
                                            const float* __restrict__ soft,
                                            unsigned short* __restrict__ xg) {
    int g = blockIdx.z, h0 = blockIdx.y * 1024, n0 = blockIdx.x * 128;
    __shared__ float smSf[128][8];
    int t = threadIdx.x;
    {
        int r = t >> 1, s4 = (t & 1) * 4;
        float4 sv = *(const float4*)&soft[(size_t)(n0 + r) * 64 + g * 8 + s4];
        smSf[r][s4 + 0] = sv.x; smSf[r][s4 + 1] = sv.y;
        smSf[r][s4 + 2] = sv.z; smSf[r][s4 + 3] = sv.w;
    }
    int hh = t * 4;
    float mu[8][4];
#pragma unroll
    for (int j = 0; j < 4; ++j) {
        const float4* p = (const float4*)(muw + ((size_t)g * H_DIM + h0 + hh + j) * 8);
        float4 a = p[0], b = p[1];
        mu[0][j] = a.x; mu[1][j] = a.y; mu[2][j] = a.z; mu[3][j] = a.w;
        mu[4][j] = b.x; mu[5][j] = b.y; mu[6][j] = b.z; mu[7][j] = b.w;
    }
    __syncthreads();
    for (int r = 0; r < 128; ++r) {
        float4 xv = *(const float4*)&x[(size_t)(n0 + r) * H_DIM + h0 + hh];
        float c0 = xv.x, c1 = xv.y, c2 = xv.z, c3 = xv.w;
#pragma unroll
        for (int s = 0; s < 8; ++s) {
            float w = smSf[r][s];
            c0 += w * mu[s][0]; c1 += w * mu[s][1];
            c2 += w * mu[s][2]; c3 += w * mu[s][3];
        }
        ushort4 o;
        o.x = f2bf(c0); o.y = f2bf(c1); o.z = f2bf(c2); o.w = f2bf(c3);
        *(ushort4*)&xg[((size_t)g * N_TOK + n0 + r) * H_DIM + h0 + hh] = o;
    }
}

// ---- gemm1: 256m x 128n dual-output (gate+up) tile, 8 waves (2M x 4N), BK=32 ----
// T3+T4+T5 pipeline, 4-deep LDS ring, counted vmcnt(8), raw s_barrier, setprio.
// Paired-row swizzle (see fragP) -> conflict-free ds_read_b128.
#define NT_G1 (H_DIM / 32)   // 64 K-tiles

__global__ __launch_bounds__(512, 2) void k_gemm1(const unsigned short* __restrict__ xg,
                                                  const unsigned short* __restrict__ wg,
                                                  const unsigned short* __restrict__ wu,
                                                  const float* __restrict__ scal,
                                                  unsigned short* __restrict__ aB) {
    int f = blockIdx.x;
    int g = f & 7, r = f >> 3;          // r in [0,88)
    int m0 = (r & 7) * 256;             // 8 m-tiles
    int n0 = (r >> 3) * 128;            // 11 n-tiles
    // 4 ring buffers x 2048 slots (A: 0..1023 = 256r x 4c | G: 1024..1535 | U: 1536..2047)
    __shared__ __align__(16) unsigned short lds[4 * 2048 * 8];   // 128 KB
    __shared__ float smS[256];
    int t = threadIdx.x, wid = t >> 6, lane = t & 63;
    int r16 = lane & 15, quad = lane >> 4;
    int wm = wid >> 2, wn = wid & 3;

    if (t < 256) smS[t] = scal[(size_t)(m0 + t) * 8 + g];

    const unsigned short* A  = xg + (size_t)g * N_TOK * H_DIM;
    const unsigned short* Bg = wg + (size_t)g * I_DIM * H_DIM;
    const unsigned short* Bu = wu + (size_t)g * I_DIM * H_DIM;

    // staging: linear LDS slot s receives global chunk (slot_row(s), slot_q(s))
    int sA0 = (wid * 2 + 0) * 64 + lane;
    int sA1 = (wid * 2 + 1) * 64 + lane;
    int sB  = wid * 64 + lane;
    const unsigned short* gA0 = A + (size_t)(m0 + slot_row(sA0)) * H_DIM + slot_q(sA0) * 8;
    const unsigned short* gA1 = A + (size_t)(m0 + slot_row(sA1)) * H_DIM + slot_q(sA1) * 8;
    const unsigned short* gG  = Bg + (size_t)(n0 + slot_row(sB)) * H_DIM + slot_q(sB) * 8;
    const unsigned short* gU  = Bu + (size_t)(n0 + slot_row(sB)) * H_DIM + slot_q(sB) * 8;

#define STAGE_A(ts) do { int b_ = (ts) & 3; \
        gl_lds16(gA0 + (size_t)(ts) * 32, &lds[((size_t)b_ * 2048 + (wid * 2 + 0) * 64) * 8]); \
        gl_lds16(gA1 + (size_t)(ts) * 32, &lds[((size_t)b_ * 2048 + (wid * 2 + 1) * 64) * 8]); } while (0)
#define STAGE_GU(ts) do { int b_ = (ts) & 3; \
        gl_lds16(gG + (size_t)(ts) * 32, &lds[((size_t)b_ * 2048 + 1024 + wid * 64) * 8]); \
        gl_lds16(gU + (size_t)(ts) * 32, &lds[((size_t)b_ * 2048 + 1536 + wid * 64) * 8]); } while (0)

    f32x4 zero = {0.f, 0.f, 0.f, 0.f};
    f32x4 accg[8][2], accu[8][2];
#pragma unroll
    for (int mi = 0; mi < 8; ++mi)
#pragma unroll
        for (int ni = 0; ni < 2; ++ni) { accg[mi][ni] = zero; accu[mi][ni] = zero; }

    // prologue: 3 K-tiles in flight; tile 0 drained, 8 newest stay pending
    STAGE_A(0); STAGE_GU(0);
    STAGE_A(1); STAGE_GU(1);
    STAGE_A(2); STAGE_GU(2);
    asm volatile("s_waitcnt vmcnt(8) lgkmcnt(0)" ::: "memory");
    __builtin_amdgcn_s_barrier();

    for (int tt = 0; tt < NT_G1; ++tt) {
        const unsigned short* buf = &lds[(size_t)(tt & 3) * 2048 * 8];
        bf16x8 af[4], bgf[2], buf_[2];
        // ---- phase 0: m-half 0 (mi 0..3) ----
#pragma unroll
        for (int mi = 0; mi < 4; ++mi)
            af[mi] = fragP(buf, 0, wm * 128 + mi * 16 + r16, quad);
#pragma unroll
        for (int ni = 0; ni < 2; ++ni) {
            bgf[ni]  = fragP(buf, 1024, wn * 32 + ni * 16 + r16, quad);
            buf_[ni] = fragP(buf, 1536, wn * 32 + ni * 16 + r16, quad);
        }
        if (tt + 3 < NT_G1) STAGE_A(tt + 3);   // into buf (tt+3)&3 == (tt-1)&3: read-complete
        __builtin_amdgcn_s_barrier();
        __builtin_amdgcn_s_setprio(1);
#pragma unroll
        for (int mi = 0; mi < 4; ++mi)
#pragma unroll
            for (int ni = 0; ni < 2; ++ni) {
                accg[mi][ni] = __builtin_amdgcn_mfma_f32_16x16x32_bf16(af[mi], bgf[ni], accg[mi][ni], 0, 0, 0);
                accu[mi][ni] = __builtin_amdgcn_mfma_f32_16x16x32_bf16(af[mi], buf_[ni], accu[mi][ni], 0, 0, 0);
            }
        __builtin_amdgcn_s_setprio(0);
        __builtin_amdgcn_s_barrier();
        // ---- phase 1: m-half 1 (mi 4..7), B frags reused ----
#pragma unroll
        for (int mi = 0; mi < 4; ++mi)
            af[mi] = fragP(buf, 0, wm * 128 + (mi + 4) * 16 + r16, quad);
        if (tt + 3 < NT_G1) STAGE_GU(tt + 3);
        __builtin_amdgcn_s_barrier();
        __builtin_amdgcn_s_setprio(1);
#pragma unroll
        for (int mi = 0; mi < 4; ++mi)
#pragma unroll
            for (int ni = 0; ni < 2; ++ni) {
                accg[mi + 4][ni] = __builtin_amdgcn_mfma_f32_16x16x32_bf16(af[mi], bgf[ni], accg[mi + 4][ni], 0, 0, 0);
                accu[mi + 4][ni] = __builtin_amdgcn_mfma_f32_16x16x32_bf16(af[mi], buf_[ni], accu[mi + 4][ni], 0, 0, 0);
            }
        __builtin_amdgcn_s_setprio(0);
        // counted wait: tile tt+1 must be landed; tiles tt+2, tt+3 stay in flight
        {
            int rem = NT_G1 - 2 - tt;
            if (rem >= 2)      asm volatile("s_waitcnt vmcnt(8)" ::: "memory");
            else if (rem == 1) asm volatile("s_waitcnt vmcnt(4)" ::: "memory");
            else if (rem == 0) asm volatile("s_waitcnt vmcnt(0)" ::: "memory");
        }
        __builtin_amdgcn_s_barrier();
    }
#undef STAGE_A
#undef STAGE_GU

#pragma unroll
    for (int mi = 0; mi < 8; ++mi)
#pragma unroll
        for (int ni = 0; ni < 2; ++ni)
#pragma unroll
            for (int rr = 0; rr < 4; ++rr) {
                int rl = wm * 128 + mi * 16 + quad * 4 + rr;
                int row = m0 + rl;
                int col = n0 + wn * 32 + ni * 16 + r16;
                float gv = accg[mi][ni][rr];
                float sv = gv / (1.0f + __expf(-gv));
                aB[((size_t)row * G_GRP + g) * I_DIM + col] = f2bf(sv * accu[mi][ni][rr] * smS[rl]);
            }
}

// ---- gemm2: y[n,h] = A'[n,:] . Wd'[h,:], 256m x 256n tile, split-K=4 (256 blocks) ----
// Same T3+T4+T5 pipeline + paired-row swizzle as gemm1. 16 MFMA/phase, BK=32, 4-deep ring.
#define NT_G2 (KTOT / 4 / 32)   // 88 K-tiles per block

__global__ __launch_bounds__(512, 2) void k_gemm2(const unsigned short* __restrict__ aB,
                                                  const unsigned short* __restrict__ wd,
                                                  float* __restrict__ out) {
    int m0 = blockIdx.x * 256, h0 = blockIdx.y * 256;
    int kbase = blockIdx.z * (KTOT / 4);   // 2816
    // 4 ring buffers x 2048 slots (A: 0..1023 = 256r x 4c | B: 1024..2047 = 256r x 4c)
    __shared__ __align__(16) unsigned short lds[4 * 2048 * 8];   // 128 KB
    int t = threadIdx.x, wid = t >> 6, lane = t & 63;
    int r16 = lane & 15, quad = lane >> 4;
    int wm = wid >> 2, wn = wid & 3;

    int sA0 = (wid * 2 + 0) * 64 + lane;
    int sA1 = (wid * 2 + 1) * 64 + lane;
    const unsigned short* gA0 = aB + (size_t)(m0 + slot_row(sA0)) * KTOT + kbase + slot_q(sA0) * 8;
    const unsigned short* gA1 = aB + (size_t)(m0 + slot_row(sA1)) * KTOT + kbase + slot_q(sA1) * 8;
    const unsigned short* gB0 = wd + (size_t)(h0 + slot_row(sA0)) * KTOT + kbase + slot_q(sA0) * 8;
    const unsigned short* gB1 = wd + (size_t)(h0 + slot_row(sA1)) * KTOT + kbase + slot_q(sA1) * 8;

#define STAGE2A(ts) do { int b_ = (ts) & 3; \
        gl_lds16(gA0 + (size_t)(ts) * 32, &lds[((size_t)b_ * 2048 + (wid * 2 + 0) * 64) * 8]); \
        gl_lds16(gA1 + (size_t)(ts) * 32, &lds[((size_t)b_ * 2048 + (wid * 2 + 1) * 64) * 8]); } while (0)
#define STAGE2B(ts) do { int b_ = (ts) & 3; \
        gl_lds16(gB0 + (size_t)(ts) * 32, &lds[((size_t)b_ * 2048 + 1024 + (wid * 2 + 0) * 64) * 8]); \
        gl_lds16(gB1 + (size_t)(ts) * 32, &lds[((size_t)b_ * 2048 + 1024 + (wid * 2 + 1) * 64) * 8]); } while (0)

    f32x4 zero = {0.f, 0.f, 0.f, 0.f};
    f32x4 acc[8][4];
#pragma unroll
    for (int mi = 0; mi < 8; ++mi)
#pragma unroll
        for (int ni = 0; ni < 4; ++ni) acc[mi][ni] = zero;

    STAGE2A(0); STAGE2B(0);
    STAGE2A(1); STAGE2B(1);
    STAGE2A(2); STAGE2B(2);
    asm volatile("s_waitcnt vmcnt(8)" ::: "memory");
    __builtin_amdgcn_s_barrier();

    for (int tt = 0; tt < NT_G2; ++tt) {
        const unsigned short* buf = &lds[(size_t)(tt & 3) * 2048 * 8];
        bf16x8 af[4], bf_[4];
        // ---- phase 0: m-half 0 ----
#pragma unroll
        for (int mi = 0; mi < 4; ++mi)
            af[mi] = fragP(buf, 0, wm * 128 + mi * 16 + r16, quad);
#pragma unroll
        for (int ni = 0; ni < 4; ++ni)
            bf_[ni] = fragP(buf, 1024, wn * 64 + ni * 16 + r16, quad);
        if (tt + 3 < NT_G2) STAGE2A(tt + 3);
        __builtin_amdgcn_s_barrier();
        __builtin_amdgcn_s_setprio(1);
#pragma unroll
        for (int mi = 0; mi < 4; ++mi)
#pragma unroll
            for (int ni = 0; ni < 4; ++ni)
                acc[mi][ni] = __builtin_amdgcn_mfma_f32_16x16x32_bf16(af[mi], bf_[ni], acc[mi][ni], 0, 0, 0);
        __builtin_amdgcn_s_setprio(0);
        __builtin_amdgcn_s_barrier();
        // ---- phase 1: m-half 1, B frags reused ----
#pragma unroll
        for (int mi = 0; mi < 4; ++mi)
            af[mi] = fragP(buf, 0, wm * 128 + (mi + 4) * 16 + r16, quad);
        if (tt + 3 < NT_G2) STAGE2B(tt + 3);
        __builtin_amdgcn_s_barrier();
        __builtin_amdgcn_s_setprio(1);
#pragma unroll
        for (int mi = 0; mi < 4; ++mi)
#pragma unroll
            for (int ni = 0; ni < 4; ++ni)
                acc[mi + 4][ni] = __builtin_amdgcn_mfma_f32_16x16x32_bf16(af[mi], bf_[ni], acc[mi + 4][ni], 0, 0, 0);
        __builtin_amdgcn_s_setprio(0);
        {
            int rem = NT_G2 - 2 - tt;
            if (rem >= 2)      asm volatile("s_waitcnt vmcnt(8)" ::: "memory");
            else if (rem == 1) asm volatile("s_waitcnt vmcnt(4)" ::: "memory");
            else if (rem == 0) asm volatile("s_waitcnt vmcnt(0)" ::: "memory");
        }
        __builtin_amdgcn_s_barrier();
    }
#undef STAGE2A
#undef STAGE2B

#pragma unroll
    for (int mi = 0; mi < 8; ++mi)
#pragma unroll
        for (int ni = 0; ni < 4; ++ni)
#pragma unroll
            for (int rr = 0; rr < 4; ++rr) {
                int row = m0 + wm * 128 + mi * 16 + quad * 4 + rr;
                int col = h0 + wn * 64 + ni * 16 + r16;
                atomicAdd(&out[(size_t)row * H_DIM + col], acc[mi][ni][rr]);
            }
}

extern "C" void kernel_launch(void* const* d_in, const int* in_sizes, int n_in,
                              void* d_out, int out_size, void* d_ws, size_t ws_size,
                              hipStream_t stream) {
    const float* x   = (const float*)d_in[0];
    const float* gw  = (const float*)d_in[1];
    const float* mu  = (const float*)d_in[2];
    const float* wgp = (const float*)d_in[3];
    const float* wup = (const float*)d_in[4];
    const float* wdp = (const float*)d_in[5];
    float* out = (float*)d_out;
    char* ws = (char*)d_ws;

    // workspace layout (241.1 MB total)
    float* gwT  = (float*)(ws + 0);                      // 512 KB
    float* soft = (float*)(ws + 524288);                 // 512 KB
    float* scal = (float*)(ws + 1048576);                // 64 KB
    unsigned short* wgB = (unsigned short*)(ws + 1114112);    // 44 MB [g][i][h]
    unsigned short* wuB = (unsigned short*)(ws + 47251456);   // 44 MB [g][i][h]
    unsigned short* wdB = (unsigned short*)(ws + 93388800);   // 44 MB [h][g*I+i]
    unsigned short* xg  = (unsigned short*)(ws + 139526144);  // 64 MB [g][n][h]
    unsigned short* aB  = (unsigned short*)(ws + 206635008);  // 44 MB [n][g*I+i]

    hipMemsetAsync(d_out, 0, (size_t)N_TOK * H_DIM * sizeof(float), stream);
    k_prep<<<3 * NQB + 512, 256, 0, stream>>>(gw, wgp, wup, wdp, gwT, wgB, wuB, wdB);
    k_gating<<<N_TOK / 8, 512, 0, stream>>>(x, gwT, soft, scal);
    k_xg<<<dim3(16, 2, 8), 256, 0, stream>>>(x, mu, soft, xg);
    k_gemm1<<<704, 512, 0, stream>>>(xg, wgB, wuB, scal, aB);
    k_gemm2<<<dim3(8, 8, 4), 512, 0, stream>>>(aB, wdB, out);
}

// Round 3
// 702.880 us; speedup vs baseline: 1.1710x; 1.0483x over previous
//
#include <hip/hip_runtime.h>

#define N_TOK 2048
#define H_DIM 2048
#define I_DIM 1408
#define E_EXP 64
#define G_GRP 8
#define KTOT  (G_GRP * I_DIM)   // 11264
#define NQ    (G_GRP * I_DIM * H_DIM / 4)   // quads per weight array = 5,767,168
#define NQB   (NQ / 256)                    // 22528 blocks per array

typedef __bf16 bf16x8 __attribute__((ext_vector_type(8)));
typedef float f32x4 __attribute__((ext_vector_type(4)));

__device__ __forceinline__ unsigned short f2bf(float f) {
    unsigned int u = __builtin_bit_cast(unsigned int, f);
    u += 0x7fffu + ((u >> 16) & 1u);   // RNE
    return (unsigned short)(u >> 16);
}

__device__ __forceinline__ void gl_lds16(const void* g, void* l) {
    __builtin_amdgcn_global_load_lds(
        (const __attribute__((address_space(1))) unsigned int*)g,
        (__attribute__((address_space(3))) unsigned int*)l, 16, 0, 0);
}

// Paired-row XOR swizzle for BK=32 tiles: two 64B rows share one 128B line so the
// XOR spans the full 8x16B bank period.  slot(row,q) = (row>>1)*8 + ((q+4*(row&1)) ^ ((row>>1)&7)).
// Verified conflict-free (round 2: SQ_LDS_BANK_CONFLICT 1.73e7 -> 0).
__device__ __forceinline__ bf16x8 fragP(const unsigned short* sm, int region, int row, int q) {
    int idx = region + ((row >> 1) << 3) + ((q | ((row & 1) << 2)) ^ ((row >> 1) & 7));
    return *(const bf16x8*)&sm[idx * 8];
}
// inverse map: linear LDS slot s -> (row, chunk q) of the global tile
__device__ __forceinline__ int slot_row(int s) {
    int line = s >> 3, u = (s & 7) ^ (line & 7);
    return (line << 1) | (u >> 2);
}
__device__ __forceinline__ int slot_q(int s) {
    int line = s >> 3, u = (s & 7) ^ (line & 7);
    return u & 3;
}

// ---------- prep: 3x fp32->bf16 weight cvt (+wd transpose) + gate_w transpose ----------
__global__ __launch_bounds__(256) void k_prep(const float* __restrict__ gw,
                                              const float* __restrict__ wgp,
                                              const float* __restrict__ wup,
                                              const float* __restrict__ wdp,
                                              float* __restrict__ gwT,
                                              unsigned short* __restrict__ wgB,
                                              unsigned short* __restrict__ wuB,
                                              unsigned short* __restrict__ wdB) {
    int b = blockIdx.x, t = threadIdx.x;
    if (b < 2 * NQB) {   // layout-preserving cvt of wg / wu
        const float* in = (b < NQB) ? wgp : wup;
        unsigned short* out = (b < NQB) ? wgB : wuB;
        int i = (b < NQB ? b : b - NQB) * 256 + t;
        float4 v = ((const float4*)in)[i];
        ushort4 o;
        o.x = f2bf(v.x); o.y = f2bf(v.y); o.z = f2bf(v.z); o.w = f2bf(v.w);
        ((ushort4*)out)[i] = o;
    } else if (b < 3 * NQB) {  // wd: [g][h][i] f32 -> [h][g*I+i] bf16
        int idx = (b - 2 * NQB) * 256 + t;
        int i4 = idx % (I_DIM / 4);
        int h  = (idx / (I_DIM / 4)) & (H_DIM - 1);
        int g  = idx / ((I_DIM / 4) * H_DIM);
        float4 v = ((const float4*)(wdp + ((size_t)g * H_DIM + h) * I_DIM))[i4];
        ushort4 o;
        o.x = f2bf(v.x); o.y = f2bf(v.y); o.z = f2bf(v.z); o.w = f2bf(v.w);
        ((ushort4*)(wdB + ((size_t)h * G_GRP + g) * I_DIM))[i4] = o;
    } else {                   // gate_w transpose [64][2048] -> [2048][64]
        int i = (b - 3 * NQB) * 256 + t;
        gwT[i] = gw[(i & 63) * H_DIM + (i >> 6)];
    }
}

// ---------------- gating: logits (f64 acc) + softmax + top8 + group softmax ----------------
__global__ __launch_bounds__(512) void k_gating(const float* __restrict__ x,
                                                const float* __restrict__ gwT,
                                                float* __restrict__ soft,
                                                float* __restrict__ scal) {
    __shared__ double smAcc[8][8][64];
    int t = threadIdx.x, wid = t >> 6, lane = t & 63;
    int n0 = blockIdx.x * 8;

    double acc[8];
#pragma unroll
    for (int k = 0; k < 8; ++k) acc[k] = 0.0;
    int h0 = wid * 256;
    for (int h = h0; h < h0 + 256; ++h) {
        float gv = gwT[h * 64 + lane];
#pragma unroll
        for (int tok = 0; tok < 8; ++tok)
            acc[tok] += (double)x[(size_t)(n0 + tok) * H_DIM + h] * (double)gv;
    }
#pragma unroll
    for (int tok = 0; tok < 8; ++tok) smAcc[wid][tok][lane] = acc[tok];
    __syncthreads();

    double lg = 0.0;
#pragma unroll
    for (int w2 = 0; w2 < 8; ++w2) lg += smAcc[w2][wid][lane];
    float logit = (float)lg;

    float mx = logit;
#pragma unroll
    for (int d = 1; d < 64; d <<= 1) mx = fmaxf(mx, __shfl_xor(mx, d));
    float ex = expf(logit - mx);
    float sm = ex;
#pragma unroll
    for (int d = 1; d < 64; d <<= 1) sm += __shfl_xor(sm, d);
    float prob = ex / sm;

    float cur = prob, w = 0.0f;
#pragma unroll
    for (int it = 0; it < 8; ++it) {
        float m = cur;
#pragma unroll
        for (int d = 1; d < 64; d <<= 1) m = fmaxf(m, __shfl_xor(m, d));
        unsigned long long msk = __ballot(cur == m);
        int first = __ffsll(msk) - 1;
        if (lane == first) { w = prob; cur = -1.0f; }
    }
    float wf = w;

    float s8 = wf;
#pragma unroll
    for (int d = 1; d < 8; d <<= 1) s8 += __shfl_xor(s8, d);
    float v = (wf == 0.0f) ? -1000000000.0f : wf;
    float m8 = v;
#pragma unroll
    for (int d = 1; d < 8; d <<= 1) m8 = fmaxf(m8, __shfl_xor(m8, d));
    float e8 = expf(v - m8);
    float q8 = e8;
#pragma unroll
    for (int d = 1; d < 8; d <<= 1) q8 += __shfl_xor(q8, d);

    int n = n0 + wid;
    soft[(size_t)n * 64 + lane] = e8 / q8;
    if ((lane & 7) == 0) scal[(size_t)n * 8 + (lane >> 3)] = s8;
}

// ------- xg[g][n][h] = bf16(x + soft.mu), vectorized: thread owns 4 h-cols, mu in regs -------
__global__ __launch_bounds__(256) void k_xg(const float* __restrict__ x,
                                            const float* __restrict__ muw,
                                            const float* __restrict__ soft,
                                            unsigned short* __restrict__ xg) {
    int g = blockIdx.z, h0 = blockIdx.y * 1024, n0 = blockIdx.x * 128;
    __shared__ float smSf[128][8];
    int t = threadIdx.x;
    {
        int r = t >> 1, s4 = (t & 1) * 4;
        float4 sv = *(const float4*)&soft[(size_t)(n0 + r) * 64 + g * 8 + s4];
        smSf[r][s4 + 0] = sv.x; smSf[r][s4 + 1] = sv.y;
        smSf[r][s4 + 2] = sv.z; smSf[r][s4 + 3] = sv.w;
    }
    int hh = t * 4;
    float mu[8][4];
#pragma unroll
    for (int j = 0; j < 4; ++j) {
        const float4* p = (const float4*)(muw + ((size_t)g * H_DIM + h0 + hh + j) * 8);
        float4 a = p[0], b = p[1];
        mu[0][j] = a.x; mu[1][j] = a.y; mu[2][j] = a.z; mu[3][j] = a.w;
        mu[4][j] = b.x; mu[5][j] = b.y; mu[6][j] = b.z; mu[7][j] = b.w;
    }
    __syncthreads();
    for (int r = 0; r < 128; ++r) {
        float4 xv = *(const float4*)&x[(size_t)(n0 + r) * H_DIM + h0 + hh];
        float c0 = xv.x, c1 = xv.y, c2 = xv.z, c3 = xv.w;
#pragma unroll
        for (int s = 0; s < 8; ++s) {
            float w = smSf[r][s];
            c0 += w * mu[s][0]; c1 += w * mu[s][1];
            c2 += w * mu[s][2]; c3 += w * mu[s][3];
        }
        ushort4 o;
        o.x = f2bf(c0); o.y = f2bf(c1); o.z = f2bf(c2); o.w = f2bf(c3);
        *(ushort4*)&xg[((size_t)g * N_TOK + n0 + r) * H_DIM + h0 + hh] = o;
    }
}

// ---- gemm1: 256m x 128n dual-output (gate+up) tile, 8 waves (2M x 4N), BK=32 ----
// Register-stage software pipeline: frags for tile tt preloaded during tile tt-1's
// window; 1 barrier + 1 counted vmcnt per K-tile; ds_reads hide under MFMA clusters.
#define NT_G1 (H_DIM / 32)   // 64 K-tiles

__global__ __launch_bounds__(512, 2) void k_gemm1(const unsigned short* __restrict__ xg,
                                                  const unsigned short* __restrict__ wg,
                                                  const unsigned short* __restrict__ wu,
                                                  const float* __restrict__ scal,
                                                  unsigned short* __restrict__ aB) {
    int f = blockIdx.x;
    int g = f & 7, r = f >> 3;          // r in [0,88)
    int m0 = (r & 7) * 256;             // 8 m-tiles
    int n0 = (r >> 3) * 128;            // 11 n-tiles
    // 4 ring buffers x 2048 slots (A: 0..1023 = 256r x 4c | G: 1024..1535 | U: 1536..2047)
    __shared__ __align__(16) unsigned short lds[4 * 2048 * 8];   // 128 KB
    __shared__ float smS[256];
    int t = threadIdx.x, wid = t >> 6, lane = t & 63;
    int r16 = lane & 15, quad = lane >> 4;
    int wm = wid >> 2, wn = wid & 3;

    if (t < 256) smS[t] = scal[(size_t)(m0 + t) * 8 + g];

    const unsigned short* A  = xg + (size_t)g * N_TOK * H_DIM;
    const unsigned short* Bg = wg + (size_t)g * I_DIM * H_DIM;
    const unsigned short* Bu = wu + (size_t)g * I_DIM * H_DIM;

    // staging: linear LDS slot s receives global chunk (slot_row(s), slot_q(s))
    int sA0 = (wid * 2 + 0) * 64 + lane;
    int sA1 = (wid * 2 + 1) * 64 + lane;
    int sB  = wid * 64 + lane;
    const unsigned short* gA0 = A + (size_t)(m0 + slot_row(sA0)) * H_DIM + slot_q(sA0) * 8;
    const unsigned short* gA1 = A + (size_t)(m0 + slot_row(sA1)) * H_DIM + slot_q(sA1) * 8;
    const unsigned short* gG  = Bg + (size_t)(n0 + slot_row(sB)) * H_DIM + slot_q(sB) * 8;
    const unsigned short* gU  = Bu + (size_t)(n0 + slot_row(sB)) * H_DIM + slot_q(sB) * 8;

#define STAGE_A(ts) do { int b_ = (ts) & 3; \
        gl_lds16(gA0 + (size_t)(ts) * 32, &lds[((size_t)b_ * 2048 + (wid * 2 + 0) * 64) * 8]); \
        gl_lds16(gA1 + (size_t)(ts) * 32, &lds[((size_t)b_ * 2048 + (wid * 2 + 1) * 64) * 8]); } while (0)
#define STAGE_GU(ts) do { int b_ = (ts) & 3; \
        gl_lds16(gG + (size_t)(ts) * 32, &lds[((size_t)b_ * 2048 + 1024 + wid * 64) * 8]); \
        gl_lds16(gU + (size_t)(ts) * 32, &lds[((size_t)b_ * 2048 + 1536 + wid * 64) * 8]); } while (0)

    f32x4 zero = {0.f, 0.f, 0.f, 0.f};
    f32x4 accg[8][2], accu[8][2];
#pragma unroll
    for (int mi = 0; mi < 8; ++mi)
#pragma unroll
        for (int ni = 0; ni < 2; ++ni) { accg[mi][ni] = zero; accu[mi][ni] = zero; }

    // prologue: 3 K-tiles in flight; wait tile 0 (keep 8 newest pending), preload frags
    STAGE_A(0); STAGE_GU(0);
    STAGE_A(1); STAGE_GU(1);
    STAGE_A(2); STAGE_GU(2);
    asm volatile("s_waitcnt vmcnt(8)" ::: "memory");
    __builtin_amdgcn_s_barrier();

    bf16x8 A0[4], BG[2], BU[2];
#pragma unroll
    for (int mi = 0; mi < 4; ++mi) A0[mi] = fragP(lds, 0, wm * 128 + mi * 16 + r16, quad);
#pragma unroll
    for (int ni = 0; ni < 2; ++ni) {
        BG[ni] = fragP(lds, 1024, wn * 32 + ni * 16 + r16, quad);
        BU[ni] = fragP(lds, 1536, wn * 32 + ni * 16 + r16, quad);
    }

#pragma unroll 2
    for (int tt = 0; tt < NT_G1 - 1; ++tt) {
        const unsigned short* buf  = &lds[(size_t)(tt & 3) * 2048 * 8];
        const unsigned short* bufn = &lds[(size_t)((tt + 1) & 3) * 2048 * 8];
        if (tt + 3 < NT_G1) { STAGE_A(tt + 3); STAGE_GU(tt + 3); }
        bf16x8 A1[4];
#pragma unroll
        for (int mi = 0; mi < 4; ++mi) A1[mi] = fragP(buf, 0, wm * 128 + (mi + 4) * 16 + r16, quad);
        __builtin_amdgcn_s_setprio(1);
#pragma unroll
        for (int mi = 0; mi < 4; ++mi)
#pragma unroll
            for (int ni = 0; ni < 2; ++ni) {
                accg[mi][ni] = __builtin_amdgcn_mfma_f32_16x16x32_bf16(A0[mi], BG[ni], accg[mi][ni], 0, 0, 0);
                accu[mi][ni] = __builtin_amdgcn_mfma_f32_16x16x32_bf16(A0[mi], BU[ni], accu[mi][ni], 0, 0, 0);
            }
        __builtin_amdgcn_s_setprio(0);
        {
            int rem = NT_G1 - 1 - tt;   // outstanding staged tiles beyond tt
            if (rem >= 3)      asm volatile("s_waitcnt vmcnt(8)" ::: "memory");
            else if (rem == 2) asm volatile("s_waitcnt vmcnt(4)" ::: "memory");
            else               asm volatile("s_waitcnt vmcnt(0)" ::: "memory");
        }
        __builtin_amdgcn_s_barrier();
        bf16x8 nA0[4], nBG[2], nBU[2];
#pragma unroll
        for (int mi = 0; mi < 4; ++mi) nA0[mi] = fragP(bufn, 0, wm * 128 + mi * 16 + r16, quad);
#pragma unroll
        for (int ni = 0; ni < 2; ++ni) {
            nBG[ni] = fragP(bufn, 1024, wn * 32 + ni * 16 + r16, quad);
            nBU[ni] = fragP(bufn, 1536, wn * 32 + ni * 16 + r16, quad);
        }
        __builtin_amdgcn_s_setprio(1);
#pragma unroll
        for (int mi = 0; mi < 4; ++mi)
#pragma unroll
            for (int ni = 0; ni < 2; ++ni) {
                accg[mi + 4][ni] = __builtin_amdgcn_mfma_f32_16x16x32_bf16(A1[mi], BG[ni], accg[mi + 4][ni], 0, 0, 0);
                accu[mi + 4][ni] = __builtin_amdgcn_mfma_f32_16x16x32_bf16(A1[mi], BU[ni], accu[mi + 4][ni], 0, 0, 0);
            }
        __builtin_amdgcn_s_setprio(0);
#pragma unroll
        for (int mi = 0; mi < 4; ++mi) A0[mi] = nA0[mi];
#pragma unroll
        for (int ni = 0; ni < 2; ++ni) { BG[ni] = nBG[ni]; BU[ni] = nBU[ni]; }
    }
    {   // last K-tile: all frags local, no staging/barrier
        const unsigned short* buf = &lds[(size_t)((NT_G1 - 1) & 3) * 2048 * 8];
        bf16x8 A1[4];
#pragma unroll
        for (int mi = 0; mi < 4; ++mi) A1[mi] = fragP(buf, 0, wm * 128 + (mi + 4) * 16 + r16, quad);
#pragma unroll
        for (int mi = 0; mi < 4; ++mi)
#pragma unroll
            for (int ni = 0; ni < 2; ++ni) {
                accg[mi][ni] = __builtin_amdgcn_mfma_f32_16x16x32_bf16(A0[mi], BG[ni], accg[mi][ni], 0, 0, 0);
                accu[mi][ni] = __builtin_amdgcn_mfma_f32_16x16x32_bf16(A0[mi], BU[ni], accu[mi][ni], 0, 0, 0);
            }
#pragma unroll
        for (int mi = 0; mi < 4; ++mi)
#pragma unroll
            for (int ni = 0; ni < 2; ++ni) {
                accg[mi + 4][ni] = __builtin_amdgcn_mfma_f32_16x16x32_bf16(A1[mi], BG[ni], accg[mi + 4][ni], 0, 0, 0);
                accu[mi + 4][ni] = __builtin_amdgcn_mfma_f32_16x16x32_bf16(A1[mi], BU[ni], accu[mi + 4][ni], 0, 0, 0);
            }
    }
#undef STAGE_A
#undef STAGE_GU

#pragma unroll
    for (int mi = 0; mi < 8; ++mi)
#pragma unroll
        for (int ni = 0; ni < 2; ++ni)
#pragma unroll
            for (int rr = 0; rr < 4; ++rr) {
                int rl = wm * 128 + mi * 16 + quad * 4 + rr;
                int row = m0 + rl;
                int col = n0 + wn * 32 + ni * 16 + r16;
                float gv = accg[mi][ni][rr];
                float sv = gv / (1.0f + __expf(-gv));
                aB[((size_t)row * G_GRP + g) * I_DIM + col] = f2bf(sv * accu[mi][ni][rr] * smS[rl]);
            }
}

// ---- gemm2: y[n,h] = A'[n,:] . Wd'[h,:], 256m x 256n tile, split-K=4 (256 blocks) ----
// Same register-stage pipeline as gemm1: 1 barrier + 1 counted vmcnt per K-tile.
#define NT_G2 (KTOT / 4 / 32)   // 88 K-tiles per block

__global__ __launch_bounds__(512, 2) void k_gemm2(const unsigned short* __restrict__ aB,
                                                  const unsigned short* __restrict__ wd,
                                                  float* __restrict__ out) {
    int m0 = blockIdx.x * 256, h0 = blockIdx.y * 256;
    int kbase = blockIdx.z * (KTOT / 4);   // 2816
    // 4 ring buffers x 2048 slots (A: 0..1023 = 256r x 4c | B: 1024..2047 = 256r x 4c)
    __shared__ __align__(16) unsigned short lds[4 * 2048 * 8];   // 128 KB
    int t = threadIdx.x, wid = t >> 6, lane = t & 63;
    int r16 = lane & 15, quad = lane >> 4;
    int wm = wid >> 2, wn = wid & 3;

    int sA0 = (wid * 2 + 0) * 64 + lane;
    int sA1 = (wid * 2 + 1) * 64 + lane;
    const unsigned short* gA0 = aB + (size_t)(m0 + slot_row(sA0)) * KTOT + kbase + slot_q(sA0) * 8;
    const unsigned short* gA1 = aB + (size_t)(m0 + slot_row(sA1)) * KTOT + kbase + slot_q(sA1) * 8;
    const unsigned short* gB0 = wd + (size_t)(h0 + slot_row(sA0)) * KTOT + kbase + slot_q(sA0) * 8;
    const unsigned short* gB1 = wd + (size_t)(h0 + slot_row(sA1)) * KTOT + kbase + slot_q(sA1) * 8;

#define STAGE2A(ts) do { int b_ = (ts) & 3; \
        gl_lds16(gA0 + (size_t)(ts) * 32, &lds[((size_t)b_ * 2048 + (wid * 2 + 0) * 64) * 8]); \
        gl_lds16(gA1 + (size_t)(ts) * 32, &lds[((size_t)b_ * 2048 + (wid * 2 + 1) * 64) * 8]); } while (0)
#define STAGE2B(ts) do { int b_ = (ts) & 3; \
        gl_lds16(gB0 + (size_t)(ts) * 32, &lds[((size_t)b_ * 2048 + 1024 + (wid * 2 + 0) * 64) * 8]); \
        gl_lds16(gB1 + (size_t)(ts) * 32, &lds[((size_t)b_ * 2048 + 1024 + (wid * 2 + 1) * 64) * 8]); } while (0)

    f32x4 zero = {0.f, 0.f, 0.f, 0.f};
    f32x4 acc[8][4];
#pragma unroll
    for (int mi = 0; mi < 8; ++mi)
#pragma unroll
        for (int ni = 0; ni < 4; ++ni) acc[mi][ni] = zero;

    STAGE2A(0); STAGE2B(0);
    STAGE2A(1); STAGE2B(1);
    STAGE2A(2); STAGE2B(2);
    asm volatile("s_waitcnt vmcnt(8)" ::: "memory");
    __builtin_amdgcn_s_barrier();

    bf16x8 A0[4], BB[4];
#pragma unroll
    for (int mi = 0; mi < 4; ++mi) A0[mi] = fragP(lds, 0, wm * 128 + mi * 16 + r16, quad);
#pragma unroll
    for (int ni = 0; ni < 4; ++ni) BB[ni] = fragP(lds, 1024, wn * 64 + ni * 16 + r16, quad);

#pragma unroll 2
    for (int tt = 0; tt < NT_G2 - 1; ++tt) {
        const unsigned short* buf  = &lds[(size_t)(tt & 3) * 2048 * 8];
        const unsigned short* bufn = &lds[(size_t)((tt + 1) & 3) * 2048 * 8];
        if (tt + 3 < NT_G2) { STAGE2A(tt + 3); STAGE2B(tt + 3); }
        bf16x8 A1[4];
#pragma unroll
        for (int mi = 0; mi < 4; ++mi) A1[mi] = fragP(buf, 0, wm * 128 + (mi + 4) * 16 + r16, quad);
        __builtin_amdgcn_s_setprio(1);
#pragma unroll
        for (int mi = 0; mi < 4; ++mi)
#pragma unroll
            for (int ni = 0; ni < 4; ++ni)
                acc[mi][ni] = __builtin_amdgcn_mfma_f32_16x16x32_bf16(A0[mi], BB[ni], acc[mi][ni], 0, 0, 0);
        __builtin_amdgcn_s_setprio(0);
        {
            int rem = NT_G2 - 1 - tt;
            if (rem >= 3)      asm volatile("s_waitcnt vmcnt(8)" ::: "memory");
            else if (rem == 2) asm volatile("s_waitcnt vmcnt(4)" ::: "memory");
            else               asm volatile("s_waitcnt vmcnt(0)" ::: "memory");
        }
        __builtin_amdgcn_s_barrier();
        bf16x8 nA0[4], nBB[4];
#pragma unroll
        for (int mi = 0; mi < 4; ++mi) nA0[mi] = fragP(bufn, 0, wm * 128 + mi * 16 + r16, quad);
#pragma unroll
        for (int ni = 0; ni < 4; ++ni) nBB[ni] = fragP(bufn, 1024, wn * 64 + ni * 16 + r16, quad);
        __builtin_amdgcn_s_setprio(1);
#pragma unroll
        for (int mi = 0; mi < 4; ++mi)
#pragma unroll
            for (int ni = 0; ni < 4; ++ni)
                acc[mi + 4][ni] = __builtin_amdgcn_mfma_f32_16x16x32_bf16(A1[mi], BB[ni], acc[mi + 4][ni], 0, 0, 0);
        __builtin_amdgcn_s_setprio(0);
#pragma unroll
        for (int mi = 0; mi < 4; ++mi) A0[mi] = nA0[mi];
#pragma unroll
        for (int ni = 0; ni < 4; ++ni) BB[ni] = nBB[ni];
    }
    {   // last K-tile
        const unsigned short* buf = &lds[(size_t)((NT_G2 - 1) & 3) * 2048 * 8];
        bf16x8 A1[4];
#pragma unroll
        for (int mi = 0; mi < 4; ++mi) A1[mi] = fragP(buf, 0, wm * 128 + (mi + 4) * 16 + r16, quad);
#pragma unroll
        for (int mi = 0; mi < 4; ++mi)
#pragma unroll
            for (int ni = 0; ni < 4; ++ni)
                acc[mi][ni] = __builtin_amdgcn_mfma_f32_16x16x32_bf16(A0[mi], BB[ni], acc[mi][ni], 0, 0, 0);
#pragma unroll
        for (int mi = 0; mi < 4; ++mi)
#pragma unroll
            for (int ni = 0; ni < 4; ++ni)
                acc[mi + 4][ni] = __builtin_amdgcn_mfma_f32_16x16x32_bf16(A1[mi], BB[ni], acc[mi + 4][ni], 0, 0, 0);
    }
#undef STAGE2A
#undef STAGE2B

#pragma unroll
    for (int mi = 0; mi < 8; ++mi)
#pragma unroll
        for (int ni = 0; ni < 4; ++ni)
#pragma unroll
            for (int rr = 0; rr < 4; ++rr) {
                int row = m0 + wm * 128 + mi * 16 + quad * 4 + rr;
                int col = h0 + wn * 64 + ni * 16 + r16;
                atomicAdd(&out[(size_t)row * H_DIM + col], acc[mi][ni][rr]);
            }
}

extern "C" void kernel_launch(void* const* d_in, const int* in_sizes, int n_in,
                              void* d_out, int out_size, void* d_ws, size_t ws_size,
                              hipStream_t stream) {
    const float* x   = (const float*)d_in[0];
    const float* gw  = (const float*)d_in[1];
    const float* mu  = (const float*)d_in[2];
    const float* wgp = (const float*)d_in[3];
    const float* wup = (const float*)d_in[4];
    const float* wdp = (const float*)d_in[5];
    float* out = (float*)d_out;
    char* ws = (char*)d_ws;

    // workspace layout (241.1 MB total)
    float* gwT  = (float*)(ws + 0);                      // 512 KB
    float* soft = (float*)(ws + 524288);                 // 512 KB
    float* scal = (float*)(ws + 1048576);                // 64 KB
    unsigned short* wgB = (unsigned short*)(ws + 1114112);    // 44 MB [g][i][h]
    unsigned short* wuB = (unsigned short*)(ws + 47251456);   // 44 MB [g][i][h]
    unsigned short* wdB = (unsigned short*)(ws + 93388800);   // 44 MB [h][g*I+i]
    unsigned short* xg  = (unsigned short*)(ws + 139526144);  // 64 MB [g][n][h]
    unsigned short* aB  = (unsigned short*)(ws + 206635008);  // 44 MB [n][g*I+i]

    hipMemsetAsync(d_out, 0, (size_t)N_TOK * H_DIM * sizeof(float), stream);
    k_prep<<<3 * NQB + 512, 256, 0, stream>>>(gw, wgp, wup, wdp, gwT, wgB, wuB, wdB);
    k_gating<<<N_TOK / 8, 512, 0, stream>>>(x, gwT, soft, scal);
    k_xg<<<dim3(16, 2, 8), 256, 0, stream>>>(x, mu, soft, xg);
    k_gemm1<<<704, 512, 0, stream>>>(xg, wgB, wuB, scal, aB);
    k_gemm2<<<dim3(8, 8, 4), 512, 0, stream>>>(aB, wdB, out);
}